// Round 2
// 244.089 us; speedup vs baseline: 1.0986x; 1.0986x over previous
//
#include <hip/hip_runtime.h>
#include <hip/hip_bf16.h>

// B=4, L=4096, D=1024; M = B*L = 16384. ALL I/O IS FP32.
// Live path: h = (x@Wp[:,0:D]) * sigmoid(x@Wp[:,2D:3D]); out = h@W_out + b_out
// Internals: bf16 MFMA, fp32 accumulation.
//
// Deep-pipeline template (T3+T4): BM=256, BK=64, 8 waves, 128 KiB LDS dbuf,
// 4 phases/K-tile, counted vmcnt(4) (never drained in-loop), T2 LDS XOR
// swizzle (slot^=row&7 on 128B rows; linear LDS dest + inverse-swizzled
// global source per rule #21), T5 setprio around MFMA, T1 XCD block swizzle.
//
// Register-pressure discipline: ONE A-fragment set (32 VGPR), re-read A-h0
// from LDS at p3 instead of keeping it live p0->p3. Guarantees no scratch
// spills in the K-loop (spill buffer-ops would corrupt counted vmcnt).
//
// Pipeline (K-tiles kt=0..15, buf b=kt&1, nb=other):
//   reads: p0:{A r0,r1 | B j0}  p1:{A r2,r3}  p2:{B j1}  p3:{A r0,r1 again}
//   stages: p0->nb:{A r0, Bg r1}(kt+1)  p1->nb:{A r1, Bo r1}(kt+1)
//           p2->b :{Bg r0, Bo r0}(kt+2) p3->b :{A r2, A r3}(kt+2)
//   every stage targets a region whose last LDS-read is >=2 barriers old;
//   vmcnt(4) at p3 leaves exactly tile kt+2's 4 partial loads in flight and
//   proves tile kt+1 fully landed before group kt+1 begins.
//
// Memory plan (ws_size-adaptive, branch constant across calls => graph-safe):
//   ws shorts [0,3M)   : WgT | WoT | WoutT bf16 panels (6 MB)
//   BIG ws (>=38 MB)   : H (16M shorts) entirely at ws+3M; single gemm2 launch.
//   SMALL ws           : H rows 0..8191 -> d_out shorts [16M,24M);
//                        H rows 8192..  -> ws+3M; two sequential gemm2 halves.
//   d_out shorts [0,16M): Xbf16 during phases 1-3, then fp32 out rows 0..8191.

#define MTOT 16384
#define DM   1024
#define MEG  (1024 * 1024)

typedef __bf16 bf16x8 __attribute__((ext_vector_type(8)));
typedef float  f32x4  __attribute__((ext_vector_type(4)));

#define AS1 __attribute__((address_space(1)))
#define AS3 __attribute__((address_space(3)))

static __device__ __forceinline__ void async_load16(const void* g, void* l) {
    __builtin_amdgcn_global_load_lds((const AS1 void*)g, (AS3 void*)l, 16, 0, 0);
}

static __device__ __forceinline__ unsigned short f2bf(float f) {
    __hip_bfloat16 h = __float2bfloat16(f);
    return *(unsigned short*)&h;
}

// ---------------- x (fp32) -> Xbf16 ------------------------------------------
__global__ __launch_bounds__(256)
void conv_x(const float* __restrict__ x, unsigned short* __restrict__ dst) {
    const size_t i = ((size_t)blockIdx.x * 256 + threadIdx.x) * 8;
    const f32x4 a = *(const f32x4*)(x + i);
    const f32x4 b = *(const f32x4*)(x + i + 4);
    __align__(16) unsigned short o[8];
    o[0] = f2bf(a[0]); o[1] = f2bf(a[1]); o[2] = f2bf(a[2]); o[3] = f2bf(a[3]);
    o[4] = f2bf(b[0]); o[5] = f2bf(b[1]); o[6] = f2bf(b[2]); o[7] = f2bf(b[3]);
    *(uint4*)(dst + i) = *(const uint4*)o;
}

// -------- weight transpose+convert: dst[n][k] = bf16(src[k][coff+n]) ---------
__global__ void transpose_w(const float* __restrict__ Wproj, const float* __restrict__ Wout,
                            unsigned short* __restrict__ dst0) {
    __shared__ unsigned short t[32][33];
    const int z = blockIdx.z;
    const float* src;
    unsigned short* dst;
    int ld, coff;
    if (z == 0)      { src = Wproj; ld = 3072; coff = 0;    dst = dst0; }
    else if (z == 1) { src = Wproj; ld = 3072; coff = 2048; dst = dst0 + MEG; }
    else             { src = Wout;  ld = 1024; coff = 0;    dst = dst0 + 2 * MEG; }
    const int k0 = blockIdx.x * 32;
    const int n0 = blockIdx.y * 32;
    const int tx = threadIdx.x, ty = threadIdx.y;
    for (int i = ty; i < 32; i += 8)
        t[i][tx] = f2bf(src[(size_t)(k0 + i) * ld + coff + n0 + tx]);
    __syncthreads();
    for (int i = ty; i < 32; i += 8)
        dst[(size_t)(n0 + i) * DM + k0 + tx] = t[tx][i];
}

// ---------- GEMM1 fused: H = (X@Wg + bg) * sigmoid(X@Wo + bo) ---------------
// 512 thr / 8 waves (2M x 4N); BM=256, BN=128 (x2 matrices), BK=64.
__global__ __launch_bounds__(512)
void gemm1_fused(const unsigned short* __restrict__ X,
                 const unsigned short* __restrict__ WgT,
                 const unsigned short* __restrict__ WoT,
                 const float* __restrict__ bproj,
                 unsigned short* __restrict__ Hlo,
                 unsigned short* __restrict__ Hhi) {
    __shared__ __align__(16) unsigned short sA[2][256 * 64];
    __shared__ __align__(16) unsigned short sB[2][256 * 64];

    const int tid  = threadIdx.x;
    const int wave = tid >> 6;
    const int lane = tid & 63;
    const int wm = wave & 1;
    const int wn = wave >> 1;

    // T1: bijective XCD swizzle (512 blocks, 512%8==0)
    const int bid = blockIdx.x;
    const int swz = (bid & 7) * 64 + (bid >> 3);
    const int m0 = (swz >> 3) * 256;
    const int n0 = (swz & 7) * 128;

    unsigned short* __restrict__ H =
        (m0 < 8192) ? Hlo : (Hhi - (size_t)8192 * DM);

    // swizzled ds_read_b128 lane constants:
    // byte(row,slot) = row*128 + (slot^(row&7))*16, slot = kk*4 + (lane>>4)
    const int rA = lane & 15;
    const int qq = lane >> 4;
    const int r7 = rA & 7;
    const int swq   = ((qq ^ (r7 & 3)) << 4);
    const int k0off = ((rA >> 2) & 1) << 6;
    const int k1off = k0off ^ 64;
    const int ldsA_base = (wm * 64 + rA) * 128 + swq;
    const int ldsB_base = (wn * 16 + rA) * 128 + swq;

    // staging: linear LDS dest (rule #21), inverse-swizzled global source
    const int trow = tid >> 3;
    const int tsw  = (((tid & 7) ^ (trow & 7)) << 4);
    const char* srcA  = (const char*)X   + (size_t)(m0 + trow) * 2048 + tsw;
    const char* srcBg = (const char*)WgT + (size_t)(n0 + trow) * 2048 + tsw;
    const char* srcBo = (const char*)WoT + (size_t)(n0 + trow) * 2048 + tsw;
    char* dA = (char*)&sA[0][0] + tid * 16;
    char* dB = (char*)&sB[0][0] + tid * 16;

#define STA1(b, kt, r)  async_load16(srcA  + (kt) * 128 + (r) * 131072, dA + (b) * 32768 + (r) * 8192)
#define STBG1(b, kt, r) async_load16(srcBg + (kt) * 128 + (r) * 131072, dB + (b) * 32768 + (r) * 8192)
#define STBO1(b, kt, r) async_load16(srcBo + (kt) * 128 + (r) * 131072, dB + (b) * 32768 + (2 + (r)) * 8192)
#define LDA1(dst, bb, h, il, kof) dst = *(const bf16x8*)((const char*)sA + (bb) * 32768 + ldsA_base + (h) * 16384 + (il) * 2048 + (kof))
#define LDB1(dst, bb, mat, j, kof) dst = *(const bf16x8*)((const char*)sB + (bb) * 32768 + ldsB_base + (mat) * 16384 + (j) * 8192 + (kof))

    f32x4 aG[2][4][2], aO[2][4][2];
    bf16x8 fa[4][2], fbg[2], fbo[2];

    // prologue: tile0 complete (8 loads), then tile1's {Bg r0, Bo r0, A r2, A r3}
    STA1(0, 0, 0); STA1(0, 0, 1); STA1(0, 0, 2); STA1(0, 0, 3);
    STBG1(0, 0, 0); STBG1(0, 0, 1); STBO1(0, 0, 0); STBO1(0, 0, 1);
    STBG1(1, 1, 0); STBO1(1, 1, 0); STA1(1, 1, 2); STA1(1, 1, 3);

#pragma unroll
    for (int h = 0; h < 2; ++h)
#pragma unroll
        for (int il = 0; il < 4; ++il)
#pragma unroll
            for (int jl = 0; jl < 2; ++jl) {
                aG[h][il][jl] = (f32x4){0.f, 0.f, 0.f, 0.f};
                aO[h][il][jl] = (f32x4){0.f, 0.f, 0.f, 0.f};
            }

    asm volatile("s_waitcnt vmcnt(4)" ::: "memory");   // tile0 landed
    __builtin_amdgcn_s_barrier();

#define MM1(H_, JL) do { \
    _Pragma("unroll") \
    for (int il = 0; il < 4; ++il) { \
        aG[H_][il][JL] = __builtin_amdgcn_mfma_f32_16x16x32_bf16(fa[il][0], fbg[0], aG[H_][il][JL], 0, 0, 0); \
        aO[H_][il][JL] = __builtin_amdgcn_mfma_f32_16x16x32_bf16(fa[il][0], fbo[0], aO[H_][il][JL], 0, 0, 0); \
        aG[H_][il][JL] = __builtin_amdgcn_mfma_f32_16x16x32_bf16(fa[il][1], fbg[1], aG[H_][il][JL], 0, 0, 0); \
        aO[H_][il][JL] = __builtin_amdgcn_mfma_f32_16x16x32_bf16(fa[il][1], fbo[1], aO[H_][il][JL], 0, 0, 0); \
    } } while (0)

#define PHASE_SYNC() \
    __builtin_amdgcn_s_barrier(); \
    asm volatile("s_waitcnt lgkmcnt(0)" ::: "memory"); \
    __builtin_amdgcn_sched_barrier(0)

#define TILE1(kt, b, nb) do { \
    /* p0: A-h0 + B-j0; stage A r0(kt+1), Bg r1(kt+1) -> nb */ \
    _Pragma("unroll") \
    for (int il = 0; il < 4; ++il) { LDA1(fa[il][0], b, 0, il, k0off); LDA1(fa[il][1], b, 0, il, k1off); } \
    LDB1(fbg[0], b, 0, 0, k0off); LDB1(fbg[1], b, 0, 0, k1off); \
    LDB1(fbo[0], b, 1, 0, k0off); LDB1(fbo[1], b, 1, 0, k1off); \
    if ((kt) < 15) { STA1(nb, (kt) + 1, 0); STBG1(nb, (kt) + 1, 1); } \
    PHASE_SYNC(); \
    __builtin_amdgcn_s_setprio(1); MM1(0, 0); __builtin_amdgcn_s_setprio(0); \
    __builtin_amdgcn_s_barrier(); \
    /* p1: A-h1; stage A r1(kt+1), Bo r1(kt+1) -> nb */ \
    _Pragma("unroll") \
    for (int il = 0; il < 4; ++il) { LDA1(fa[il][0], b, 1, il, k0off); LDA1(fa[il][1], b, 1, il, k1off); } \
    if ((kt) < 15) { STA1(nb, (kt) + 1, 1); STBO1(nb, (kt) + 1, 1); } \
    PHASE_SYNC(); \
    __builtin_amdgcn_s_setprio(1); MM1(1, 0); __builtin_amdgcn_s_setprio(0); \
    __builtin_amdgcn_s_barrier(); \
    /* p2: B-j1 (fa=h1 still live); stage Bg r0, Bo r0 (kt+2) -> b */ \
    LDB1(fbg[0], b, 0, 1, k0off); LDB1(fbg[1], b, 0, 1, k1off); \
    LDB1(fbo[0], b, 1, 1, k0off); LDB1(fbo[1], b, 1, 1, k1off); \
    if ((kt) < 14) { STBG1(b, (kt) + 2, 0); STBO1(b, (kt) + 2, 0); } \
    PHASE_SYNC(); \
    __builtin_amdgcn_s_setprio(1); MM1(1, 1); __builtin_amdgcn_s_setprio(0); \
    __builtin_amdgcn_s_barrier(); \
    /* p3: re-read A-h0 (regions intact); stage A r2,r3 (kt+2) -> b */ \
    _Pragma("unroll") \
    for (int il = 0; il < 4; ++il) { LDA1(fa[il][0], b, 0, il, k0off); LDA1(fa[il][1], b, 0, il, k1off); } \
    if ((kt) < 14) { STA1(b, (kt) + 2, 2); STA1(b, (kt) + 2, 3); } \
    PHASE_SYNC(); \
    __builtin_amdgcn_s_setprio(1); MM1(0, 1); __builtin_amdgcn_s_setprio(0); \
    if ((kt) < 14) { asm volatile("s_waitcnt vmcnt(4)" ::: "memory"); } \
    else           { asm volatile("s_waitcnt vmcnt(0)" ::: "memory"); } \
    __builtin_amdgcn_s_barrier(); \
} while (0)

#pragma unroll 1
    for (int kt2 = 0; kt2 < 16; kt2 += 2) {
        TILE1(kt2, 0, 1);
        TILE1(kt2 + 1, 1, 0);
    }
#undef TILE1
#undef MM1
#undef STA1
#undef STBG1
#undef STBO1
#undef LDA1
#undef LDB1

    const int colL = lane & 15;
    const int rowQ = (lane >> 4) * 4;
#pragma unroll
    for (int jl = 0; jl < 2; ++jl) {
        const int n = n0 + wn * 16 + jl * 64 + colL;
        const float bgv = bproj[n];
        const float bov = bproj[2048 + n];
#pragma unroll
        for (int h = 0; h < 2; ++h)
#pragma unroll
            for (int il = 0; il < 4; ++il) {
                const int mbase = m0 + wm * 64 + h * 128 + il * 16 + rowQ;
#pragma unroll
                for (int r = 0; r < 4; ++r) {
                    const float g = aG[h][il][jl][r] + bgv;
                    const float o = aO[h][il][jl][r] + bov;
                    const float hv = g * (1.0f / (1.0f + __expf(-o)));
                    H[(size_t)(mbase + r) * DM + n] = f2bf(hv);
                }
            }
    }
}

// -------- GEMM2: Out = H @ WoutT^T + b; same template, BM=256 BN=256 ---------
__global__ __launch_bounds__(512)
void gemm2(const unsigned short* __restrict__ Hlo,
           const unsigned short* __restrict__ Hhi,
           const unsigned short* __restrict__ Bt,
           const float* __restrict__ bout,
           float* __restrict__ Out,
           int row_base) {
    __shared__ __align__(16) unsigned short sA[2][256 * 64];
    __shared__ __align__(16) unsigned short sB[2][256 * 64];

    const int tid  = threadIdx.x;
    const int wave = tid >> 6;
    const int lane = tid & 63;
    const int wm = wave & 1;
    const int wn = wave >> 1;

    const int bid = blockIdx.x;
    const int q8  = (int)gridDim.x >> 3;      // grids are 256 or 128 (%8==0)
    const int swz = (bid & 7) * q8 + (bid >> 3);
    const int m0 = row_base + (swz >> 2) * 256;
    const int n0 = (swz & 3) * 256;

    const unsigned short* __restrict__ A =
        (m0 < 8192) ? (Hlo + (size_t)m0 * DM) : (Hhi + (size_t)(m0 - 8192) * DM);

    const int rA = lane & 15;
    const int qq = lane >> 4;
    const int r7 = rA & 7;
    const int swq   = ((qq ^ (r7 & 3)) << 4);
    const int k0off = ((rA >> 2) & 1) << 6;
    const int k1off = k0off ^ 64;
    const int ldsA_base = (wm * 64 + rA) * 128 + swq;
    const int ldsB_base = (wn * 16 + rA) * 128 + swq;

    const int trow = tid >> 3;
    const int tsw  = (((tid & 7) ^ (trow & 7)) << 4);
    const char* srcA = (const char*)A  + (size_t)trow * 2048 + tsw;
    const char* srcB = (const char*)Bt + (size_t)(n0 + trow) * 2048 + tsw;
    char* dA = (char*)&sA[0][0] + tid * 16;
    char* dB = (char*)&sB[0][0] + tid * 16;

#define STA2(b, kt, r) async_load16(srcA + (kt) * 128 + (r) * 131072, dA + (b) * 32768 + (r) * 8192)
#define STB2(b, kt, r) async_load16(srcB + (kt) * 128 + (r) * 131072, dB + (b) * 32768 + (r) * 8192)
#define LDA2(dst, bb, h, il, kof) dst = *(const bf16x8*)((const char*)sA + (bb) * 32768 + ldsA_base + (h) * 16384 + (il) * 2048 + (kof))
#define LDB2(dst, bb, j, kof)     dst = *(const bf16x8*)((const char*)sB + (bb) * 32768 + ldsB_base + (j) * 8192 + (kof))

    f32x4 acc[2][4][4];
    bf16x8 fa[4][2], fb[2][2];

    STA2(0, 0, 0); STA2(0, 0, 1); STA2(0, 0, 2); STA2(0, 0, 3);
    STB2(0, 0, 0); STB2(0, 0, 1); STB2(0, 0, 2); STB2(0, 0, 3);
    STB2(1, 1, 0); STB2(1, 1, 1); STA2(1, 1, 2); STA2(1, 1, 3);

#pragma unroll
    for (int h = 0; h < 2; ++h)
#pragma unroll
        for (int il = 0; il < 4; ++il)
#pragma unroll
            for (int j = 0; j < 4; ++j)
                acc[h][il][j] = (f32x4){0.f, 0.f, 0.f, 0.f};

    asm volatile("s_waitcnt vmcnt(4)" ::: "memory");
    __builtin_amdgcn_s_barrier();

#define MM2(H_, JB) do { \
    _Pragma("unroll") \
    for (int il = 0; il < 4; ++il) { \
        acc[H_][il][JB]     = __builtin_amdgcn_mfma_f32_16x16x32_bf16(fa[il][0], fb[0][0], acc[H_][il][JB], 0, 0, 0); \
        acc[H_][il][JB + 1] = __builtin_amdgcn_mfma_f32_16x16x32_bf16(fa[il][0], fb[1][0], acc[H_][il][JB + 1], 0, 0, 0); \
        acc[H_][il][JB]     = __builtin_amdgcn_mfma_f32_16x16x32_bf16(fa[il][1], fb[0][1], acc[H_][il][JB], 0, 0, 0); \
        acc[H_][il][JB + 1] = __builtin_amdgcn_mfma_f32_16x16x32_bf16(fa[il][1], fb[1][1], acc[H_][il][JB + 1], 0, 0, 0); \
    } } while (0)

#define PHASE_SYNC2() \
    __builtin_amdgcn_s_barrier(); \
    asm volatile("s_waitcnt lgkmcnt(0)" ::: "memory"); \
    __builtin_amdgcn_sched_barrier(0)

#define TILE2(kt, b, nb) do { \
    /* p0: A-h0 + B cols 0,1; stage A r0, B r2 (kt+1) -> nb */ \
    _Pragma("unroll") \
    for (int il = 0; il < 4; ++il) { LDA2(fa[il][0], b, 0, il, k0off); LDA2(fa[il][1], b, 0, il, k1off); } \
    LDB2(fb[0][0], b, 0, k0off); LDB2(fb[0][1], b, 0, k1off); \
    LDB2(fb[1][0], b, 1, k0off); LDB2(fb[1][1], b, 1, k1off); \
    if ((kt) < 15) { STA2(nb, (kt) + 1, 0); STB2(nb, (kt) + 1, 2); } \
    PHASE_SYNC2(); \
    __builtin_amdgcn_s_setprio(1); MM2(0, 0); __builtin_amdgcn_s_setprio(0); \
    __builtin_amdgcn_s_barrier(); \
    /* p1: A-h1; stage A r1, B r3 (kt+1) -> nb */ \
    _Pragma("unroll") \
    for (int il = 0; il < 4; ++il) { LDA2(fa[il][0], b, 1, il, k0off); LDA2(fa[il][1], b, 1, il, k1off); } \
    if ((kt) < 15) { STA2(nb, (kt) + 1, 1); STB2(nb, (kt) + 1, 3); } \
    PHASE_SYNC2(); \
    __builtin_amdgcn_s_setprio(1); MM2(1, 0); __builtin_amdgcn_s_setprio(0); \
    __builtin_amdgcn_s_barrier(); \
    /* p2: B cols 2,3 (fa=h1 live); stage B r0, B r1 (kt+2) -> b */ \
    LDB2(fb[0][0], b, 2, k0off); LDB2(fb[0][1], b, 2, k1off); \
    LDB2(fb[1][0], b, 3, k0off); LDB2(fb[1][1], b, 3, k1off); \
    if ((kt) < 14) { STB2(b, (kt) + 2, 0); STB2(b, (kt) + 2, 1); } \
    PHASE_SYNC2(); \
    __builtin_amdgcn_s_setprio(1); MM2(1, 2); __builtin_amdgcn_s_setprio(0); \
    __builtin_amdgcn_s_barrier(); \
    /* p3: re-read A-h0; stage A r2,r3 (kt+2) -> b */ \
    _Pragma("unroll") \
    for (int il = 0; il < 4; ++il) { LDA2(fa[il][0], b, 0, il, k0off); LDA2(fa[il][1], b, 0, il, k1off); } \
    if ((kt) < 14) { STA2(b, (kt) + 2, 2); STA2(b, (kt) + 2, 3); } \
    PHASE_SYNC2(); \
    __builtin_amdgcn_s_setprio(1); MM2(0, 2); __builtin_amdgcn_s_setprio(0); \
    if ((kt) < 14) { asm volatile("s_waitcnt vmcnt(4)" ::: "memory"); } \
    else           { asm volatile("s_waitcnt vmcnt(0)" ::: "memory"); } \
    __builtin_amdgcn_s_barrier(); \
} while (0)

#pragma unroll 1
    for (int kt2 = 0; kt2 < 16; kt2 += 2) {
        TILE2(kt2, 0, 1);
        TILE2(kt2 + 1, 1, 0);
    }
#undef TILE2
#undef MM2
#undef STA2
#undef STB2
#undef LDA2
#undef LDB2

    const int colL = lane & 15;
    const int rowQ = (lane >> 4) * 4;
#pragma unroll
    for (int j = 0; j < 4; ++j) {
        const int n = n0 + wn * 16 + j * 64 + colL;
        const float bv = bout[n];
#pragma unroll
        for (int h = 0; h < 2; ++h)
#pragma unroll
            for (int il = 0; il < 4; ++il) {
                const int mbase = m0 + wm * 64 + h * 128 + il * 16 + rowQ;
#pragma unroll
                for (int r = 0; r < 4; ++r)
                    Out[(size_t)(mbase + r) * DM + n] = acc[h][il][j][r] + bv;
            }
    }
}

extern "C" void kernel_launch(void* const* d_in, const int* in_sizes, int n_in,
                              void* d_out, int out_size, void* d_ws, size_t ws_size,
                              hipStream_t stream) {
    const float* x     = (const float*)d_in[0];   // [4,4096,1024] fp32
    const float* Wproj = (const float*)d_in[1];   // [1024,3072]   fp32
    const float* bproj = (const float*)d_in[2];   // [3072]        fp32
    const float* Wout  = (const float*)d_in[3];   // [1024,1024]   fp32
    const float* bout  = (const float*)d_in[4];   // [1024]        fp32
    float* out = (float*)d_out;                   // [4,4096,1024] fp32 (64 MB)

    unsigned short* Xb  = (unsigned short*)d_out; // shorts [0,16M): Xbf16 (phases 1-3)
    unsigned short* WgT   = (unsigned short*)d_ws;
    unsigned short* WoT   = WgT + MEG;
    unsigned short* WoutT = WgT + 2 * MEG;
    unsigned short* Hws   = WgT + 3 * MEG;

    const bool big_ws = ws_size >= (size_t)19 * MEG * 2;

    unsigned short* Hlo = big_ws ? Hws : ((unsigned short*)d_out + 16 * MEG);
    unsigned short* Hhi = big_ws ? (Hws + (size_t)8192 * DM) : Hws;

    // 1) Xbf16 (d_out lo) <- fp32 x
    conv_x<<<(MTOT * DM) / (256 * 8), 256, 0, stream>>>(x, Xb);

    // 2) transposed bf16 weight panels -> ws
    transpose_w<<<dim3(32, 32, 3), dim3(32, 8, 1), 0, stream>>>(Wproj, Wout, WgT);

    // 3) H = (X@Wg + bg) * sigmoid(X@Wo + bo), stored split across Hlo/Hhi
    gemm1_fused<<<512, 512, 0, stream>>>(Xb, WgT, WoT, bproj, Hlo, Hhi);

    // 4) out = H @ Wout + b_out
    if (big_ws) {
        gemm2<<<256, 512, 0, stream>>>(Hlo, Hhi, WoutT, bout, out, 0);
    } else {
        gemm2<<<128, 512, 0, stream>>>(Hlo, Hhi, WoutT, bout, out, 0);
        gemm2<<<128, 512, 0, stream>>>(Hlo, Hhi, WoutT, bout, out, 8192);
    }
}

// Round 3
// 243.865 us; speedup vs baseline: 1.0996x; 1.0009x over previous
//
#include <hip/hip_runtime.h>
#include <hip/hip_bf16.h>

// B=4, L=4096, D=1024; M = B*L = 16384. ALL I/O IS FP32.
// Live path: h = (x@Wp[:,0:D]) * sigmoid(x@Wp[:,2D:3D]); out = h@W_out + b_out
// Internals: bf16 MFMA, fp32 accumulation.
//
// Round-3 structure: 2 phases per K-tile, ONE barrier per phase.
//   phase = [ds_reads][stage gload_lds][lgkmcnt(0)][MFMA cluster][<vmcnt>][barrier]
// Invariants (derived, all hold with 1 barrier/phase):
//   - stage-overwrite safety: a region last-read in phase p is complete before
//     every wave's p-MFMA (own lgkmcnt(0)), hence before the p-end barrier;
//     stages targeting it issue in phase >= p+1.  OK.
//   - staged-data freshness: wave Y's counted vmcnt at p1-end precedes the
//     p1-end barrier, which precedes wave X's next-tile ds_reads.  OK.
//   - counted vmcnt: never drained to 0 in the main loop (tail only).
// T2 LDS XOR swizzle (slot^=row&7 on 128B rows; linear LDS dest +
// inverse-swizzled global source), T5 setprio, T1 XCD block swizzle.
//
// gemm1: BM=256, BN=128(x2 mats), BK=64, 8 waves (2M x 4N), LDS 128 KiB.
//   K-tile kt (buf b=kt&1, nb=b^1):
//     p0: read A-h0(8 b128) + ALL B(8); stage kt+1 {A2,A3,Bg1,Bo1}->nb; MFMA h0 (32)
//     p1: read A-h1(8);                stage kt+2 {A0,A1,Bg0,Bo0}->b;  MFMA h1 (32)
//     vmcnt(4) at p1-end: leaves kt+2's 4 in flight, proves kt+1 landed.
// gemm2: BM=256, BN=128, BK=64, 8 waves (4M x 2N), LDS 96 KiB.
//     p0: read A(8) + B(8); stage kt+1 {A2,A3,B1}->nb; MFMA j01 (16)
//     p1: (no reads);       stage kt+2 {A0,A1,B0}->b;  MFMA j23 (16); vmcnt(3)
//   8 n-blocks: small-ws halves run 256 blocks (FULL machine, fixes the
//   round-2 regression where BN=256 halves used only 128 blocks).
//
// Memory plan (ws_size-adaptive, branch constant across calls => graph-safe):
//   ws shorts [0,3M)   : WgT | WoT | WoutT bf16 panels (6 MB)
//   BIG ws (>=38 MB)   : H (16M shorts) entirely at ws+3M; single gemm2 launch.
//   SMALL ws           : H rows 0..8191 -> d_out shorts [16M,24M);
//                        H rows 8192..  -> ws+3M; two sequential gemm2 halves.
//   d_out shorts [0,16M): Xbf16 during phases 1-3, then fp32 out rows 0..8191.

#define MTOT 16384
#define DM   1024
#define MEG  (1024 * 1024)

typedef __bf16 bf16x8 __attribute__((ext_vector_type(8)));
typedef float  f32x4  __attribute__((ext_vector_type(4)));

#define AS1 __attribute__((address_space(1)))
#define AS3 __attribute__((address_space(3)))

static __device__ __forceinline__ void async_load16(const void* g, void* l) {
    __builtin_amdgcn_global_load_lds((const AS1 void*)g, (AS3 void*)l, 16, 0, 0);
}

static __device__ __forceinline__ unsigned short f2bf(float f) {
    __hip_bfloat16 h = __float2bfloat16(f);
    return *(unsigned short*)&h;
}

// ---------------- x (fp32) -> Xbf16 ------------------------------------------
__global__ __launch_bounds__(256)
void conv_x(const float* __restrict__ x, unsigned short* __restrict__ dst) {
    const size_t i = ((size_t)blockIdx.x * 256 + threadIdx.x) * 8;
    const f32x4 a = *(const f32x4*)(x + i);
    const f32x4 b = *(const f32x4*)(x + i + 4);
    __align__(16) unsigned short o[8];
    o[0] = f2bf(a[0]); o[1] = f2bf(a[1]); o[2] = f2bf(a[2]); o[3] = f2bf(a[3]);
    o[4] = f2bf(b[0]); o[5] = f2bf(b[1]); o[6] = f2bf(b[2]); o[7] = f2bf(b[3]);
    *(uint4*)(dst + i) = *(const uint4*)o;
}

// -------- weight transpose+convert: dst[n][k] = bf16(src[k][coff+n]) ---------
__global__ void transpose_w(const float* __restrict__ Wproj, const float* __restrict__ Wout,
                            unsigned short* __restrict__ dst0) {
    __shared__ unsigned short t[32][33];
    const int z = blockIdx.z;
    const float* src;
    unsigned short* dst;
    int ld, coff;
    if (z == 0)      { src = Wproj; ld = 3072; coff = 0;    dst = dst0; }
    else if (z == 1) { src = Wproj; ld = 3072; coff = 2048; dst = dst0 + MEG; }
    else             { src = Wout;  ld = 1024; coff = 0;    dst = dst0 + 2 * MEG; }
    const int k0 = blockIdx.x * 32;
    const int n0 = blockIdx.y * 32;
    const int tx = threadIdx.x, ty = threadIdx.y;
    for (int i = ty; i < 32; i += 8)
        t[i][tx] = f2bf(src[(size_t)(k0 + i) * ld + coff + n0 + tx]);
    __syncthreads();
    for (int i = ty; i < 32; i += 8)
        dst[(size_t)(n0 + i) * DM + k0 + tx] = t[tx][i];
}

// ---------- GEMM1 fused: H = (X@Wg + bg) * sigmoid(X@Wo + bo) ---------------
__global__ __launch_bounds__(512)
void gemm1_fused(const unsigned short* __restrict__ X,
                 const unsigned short* __restrict__ WgT,
                 const unsigned short* __restrict__ WoT,
                 const float* __restrict__ bproj,
                 unsigned short* __restrict__ Hlo,
                 unsigned short* __restrict__ Hhi) {
    __shared__ __align__(16) unsigned short sA[2][256 * 64];
    __shared__ __align__(16) unsigned short sB[2][256 * 64];

    const int tid  = threadIdx.x;
    const int wave = tid >> 6;
    const int lane = tid & 63;
    const int wm = wave & 1;
    const int wn = wave >> 1;

    // T1: bijective XCD swizzle (512 blocks, %8==0)
    const int bid = blockIdx.x;
    const int swz = (bid & 7) * 64 + (bid >> 3);
    const int m0 = (swz >> 3) * 256;
    const int n0 = (swz & 7) * 128;

    unsigned short* __restrict__ H =
        (m0 < 8192) ? Hlo : (Hhi - (size_t)8192 * DM);

    // swizzled ds_read_b128 lane constants:
    // byte(row,slot) = row*128 + (slot^(row&7))*16, slot = kk*4 + (lane>>4)
    const int rA = lane & 15;
    const int qq = lane >> 4;
    const int r7 = rA & 7;
    const int swq   = ((qq ^ (r7 & 3)) << 4);
    const int k0off = ((rA >> 2) & 1) << 6;
    const int k1off = k0off ^ 64;
    const int ldsA_base = (wm * 64 + rA) * 128 + swq;
    const int ldsB_base = (wn * 16 + rA) * 128 + swq;

    // staging: linear LDS dest (rule #21), inverse-swizzled global source
    const int trow = tid >> 3;
    const int tsw  = (((tid & 7) ^ (trow & 7)) << 4);
    const char* srcA  = (const char*)X   + (size_t)(m0 + trow) * 2048 + tsw;
    const char* srcBg = (const char*)WgT + (size_t)(n0 + trow) * 2048 + tsw;
    const char* srcBo = (const char*)WoT + (size_t)(n0 + trow) * 2048 + tsw;
    char* dA = (char*)&sA[0][0] + tid * 16;
    char* dB = (char*)&sB[0][0] + tid * 16;

#define STA1(b, kt, r)  async_load16(srcA  + (kt) * 128 + (r) * 131072, dA + (b) * 32768 + (r) * 8192)
#define STBG1(b, kt, r) async_load16(srcBg + (kt) * 128 + (r) * 131072, dB + (b) * 32768 + (r) * 8192)
#define STBO1(b, kt, r) async_load16(srcBo + (kt) * 128 + (r) * 131072, dB + (b) * 32768 + (2 + (r)) * 8192)
#define LDA1(dst, bb, h, il, kof) dst = *(const bf16x8*)((const char*)sA + (bb) * 32768 + ldsA_base + (h) * 16384 + (il) * 2048 + (kof))
#define LDB1(dst, bb, mat, j, kof) dst = *(const bf16x8*)((const char*)sB + (bb) * 32768 + ldsB_base + (mat) * 16384 + (j) * 8192 + (kof))

    f32x4 aG[2][4][2], aO[2][4][2];
    bf16x8 fa[4][2], fbg[2][2], fbo[2][2];

    // prologue: tile0 complete (8 loads), then tile1's {A0,A1,Bg0,Bo0}
    STA1(0, 0, 0); STA1(0, 0, 1); STA1(0, 0, 2); STA1(0, 0, 3);
    STBG1(0, 0, 0); STBG1(0, 0, 1); STBO1(0, 0, 0); STBO1(0, 0, 1);
    STA1(1, 1, 0); STA1(1, 1, 1); STBG1(1, 1, 0); STBO1(1, 1, 0);

#pragma unroll
    for (int h = 0; h < 2; ++h)
#pragma unroll
        for (int il = 0; il < 4; ++il)
#pragma unroll
            for (int jl = 0; jl < 2; ++jl) {
                aG[h][il][jl] = (f32x4){0.f, 0.f, 0.f, 0.f};
                aO[h][il][jl] = (f32x4){0.f, 0.f, 0.f, 0.f};
            }

    asm volatile("s_waitcnt vmcnt(4)" ::: "memory");   // tile0 landed
    __builtin_amdgcn_s_barrier();

#define MM1(H_) do { \
    _Pragma("unroll") \
    for (int il = 0; il < 4; ++il) { \
        _Pragma("unroll") \
        for (int jl = 0; jl < 2; ++jl) { \
            aG[H_][il][jl] = __builtin_amdgcn_mfma_f32_16x16x32_bf16(fa[il][0], fbg[jl][0], aG[H_][il][jl], 0, 0, 0); \
            aO[H_][il][jl] = __builtin_amdgcn_mfma_f32_16x16x32_bf16(fa[il][0], fbo[jl][0], aO[H_][il][jl], 0, 0, 0); \
            aG[H_][il][jl] = __builtin_amdgcn_mfma_f32_16x16x32_bf16(fa[il][1], fbg[jl][1], aG[H_][il][jl], 0, 0, 0); \
            aO[H_][il][jl] = __builtin_amdgcn_mfma_f32_16x16x32_bf16(fa[il][1], fbo[jl][1], aO[H_][il][jl], 0, 0, 0); \
        } } } while (0)

#define TILE1(kt, b, nb) do { \
    /* p0: read A-h0 + ALL B; stage kt+1's {A2,A3,Bg1,Bo1} -> nb */ \
    _Pragma("unroll") \
    for (int il = 0; il < 4; ++il) { LDA1(fa[il][0], b, 0, il, k0off); LDA1(fa[il][1], b, 0, il, k1off); } \
    _Pragma("unroll") \
    for (int jl = 0; jl < 2; ++jl) { \
        LDB1(fbg[jl][0], b, 0, jl, k0off); LDB1(fbg[jl][1], b, 0, jl, k1off); \
        LDB1(fbo[jl][0], b, 1, jl, k0off); LDB1(fbo[jl][1], b, 1, jl, k1off); } \
    if ((kt) < 15) { STA1(nb, (kt) + 1, 2); STA1(nb, (kt) + 1, 3); STBG1(nb, (kt) + 1, 1); STBO1(nb, (kt) + 1, 1); } \
    asm volatile("s_waitcnt lgkmcnt(0)" ::: "memory"); \
    __builtin_amdgcn_sched_barrier(0); \
    __builtin_amdgcn_s_setprio(1); MM1(0); __builtin_amdgcn_s_setprio(0); \
    __builtin_amdgcn_s_barrier(); \
    /* p1: read A-h1; stage kt+2's {A0,A1,Bg0,Bo0} -> b */ \
    _Pragma("unroll") \
    for (int il = 0; il < 4; ++il) { LDA1(fa[il][0], b, 1, il, k0off); LDA1(fa[il][1], b, 1, il, k1off); } \
    if ((kt) < 14) { STA1(b, (kt) + 2, 0); STA1(b, (kt) + 2, 1); STBG1(b, (kt) + 2, 0); STBO1(b, (kt) + 2, 0); } \
    asm volatile("s_waitcnt lgkmcnt(0)" ::: "memory"); \
    __builtin_amdgcn_sched_barrier(0); \
    __builtin_amdgcn_s_setprio(1); MM1(1); __builtin_amdgcn_s_setprio(0); \
    if ((kt) < 14) { asm volatile("s_waitcnt vmcnt(4)" ::: "memory"); } \
    else           { asm volatile("s_waitcnt vmcnt(0)" ::: "memory"); } \
    __builtin_amdgcn_s_barrier(); \
} while (0)

#pragma unroll 1
    for (int kt2 = 0; kt2 < 16; kt2 += 2) {
        TILE1(kt2, 0, 1);
        TILE1(kt2 + 1, 1, 0);
    }
#undef TILE1
#undef MM1
#undef STA1
#undef STBG1
#undef STBO1
#undef LDA1
#undef LDB1

    const int colL = lane & 15;
    const int rowQ = (lane >> 4) * 4;
#pragma unroll
    for (int jl = 0; jl < 2; ++jl) {
        const int n = n0 + wn * 16 + jl * 64 + colL;
        const float bgv = bproj[n];
        const float bov = bproj[2048 + n];
#pragma unroll
        for (int h = 0; h < 2; ++h)
#pragma unroll
            for (int il = 0; il < 4; ++il) {
                const int mbase = m0 + wm * 64 + h * 128 + il * 16 + rowQ;
#pragma unroll
                for (int r = 0; r < 4; ++r) {
                    const float g = aG[h][il][jl][r] + bgv;
                    const float o = aO[h][il][jl][r] + bov;
                    const float hv = g * (1.0f / (1.0f + __expf(-o)));
                    H[(size_t)(mbase + r) * DM + n] = f2bf(hv);
                }
            }
    }
}

// -------- GEMM2: Out = H @ WoutT^T + b; BM=256, BN=128, 4Mx2N waves ----------
__global__ __launch_bounds__(512)
void gemm2(const unsigned short* __restrict__ Hlo,
           const unsigned short* __restrict__ Hhi,
           const unsigned short* __restrict__ Bt,
           const float* __restrict__ bout,
           float* __restrict__ Out,
           int row_base) {
    __shared__ __align__(16) unsigned short sA[2][256 * 64];   // 4 regions / buf
    __shared__ __align__(16) unsigned short sB[2][128 * 64];   // 2 regions / buf

    const int tid  = threadIdx.x;
    const int wave = tid >> 6;
    const int lane = tid & 63;
    const int wm = wave & 3;       // 4 M-waves x 64 rows
    const int wn = wave >> 2;      // 2 N-waves x 64 cols

    const int bid = blockIdx.x;
    const int q8  = (int)gridDim.x >> 3;      // 512 or 256 blocks (%8==0)
    const int swz = (bid & 7) * q8 + (bid >> 3);
    const int m0 = row_base + (swz >> 3) * 256;
    const int n0 = (swz & 7) * 128;

    const unsigned short* __restrict__ A =
        (m0 < 8192) ? (Hlo + (size_t)m0 * DM) : (Hhi + (size_t)(m0 - 8192) * DM);

    const int rA = lane & 15;
    const int qq = lane >> 4;
    const int r7 = rA & 7;
    const int swq   = ((qq ^ (r7 & 3)) << 4);
    const int k0off = ((rA >> 2) & 1) << 6;
    const int k1off = k0off ^ 64;
    const int ldsA_base = (wm * 64 + rA) * 128 + swq;
    const int ldsB_base = (wn * 64 + rA) * 128 + swq;

    const int trow = tid >> 3;
    const int tsw  = (((tid & 7) ^ (trow & 7)) << 4);
    const char* srcA = (const char*)A  + (size_t)trow * 2048 + tsw;
    const char* srcB = (const char*)Bt + (size_t)(n0 + trow) * 2048 + tsw;
    char* dA = (char*)&sA[0][0] + tid * 16;
    char* dB = (char*)&sB[0][0] + tid * 16;

#define STA2(b, kt, r) async_load16(srcA + (kt) * 128 + (r) * 131072, dA + (b) * 32768 + (r) * 8192)
#define STB2(b, kt, r) async_load16(srcB + (kt) * 128 + (r) * 131072, dB + (b) * 16384 + (r) * 8192)
#define LDA2(dst, bb, il, kof) dst = *(const bf16x8*)((const char*)sA + (bb) * 32768 + ldsA_base + (il) * 2048 + (kof))
#define LDB2(dst, bb, jl, kof) dst = *(const bf16x8*)((const char*)sB + (bb) * 16384 + ldsB_base + (jl) * 2048 + (kof))

    f32x4 acc[4][4];
    bf16x8 fa[4][2], fb[4][2];

    // prologue: tile0 complete (6 loads), then tile1's {A0,A1,B0}
    STA2(0, 0, 0); STA2(0, 0, 1); STA2(0, 0, 2); STA2(0, 0, 3);
    STB2(0, 0, 0); STB2(0, 0, 1);
    STA2(1, 1, 0); STA2(1, 1, 1); STB2(1, 1, 0);

#pragma unroll
    for (int il = 0; il < 4; ++il)
#pragma unroll
        for (int j = 0; j < 4; ++j) acc[il][j] = (f32x4){0.f, 0.f, 0.f, 0.f};

    asm volatile("s_waitcnt vmcnt(3)" ::: "memory");   // tile0 landed
    __builtin_amdgcn_s_barrier();

#define MM2(JB) do { \
    _Pragma("unroll") \
    for (int il = 0; il < 4; ++il) { \
        acc[il][JB]     = __builtin_amdgcn_mfma_f32_16x16x32_bf16(fa[il][0], fb[JB][0], acc[il][JB], 0, 0, 0); \
        acc[il][JB + 1] = __builtin_amdgcn_mfma_f32_16x16x32_bf16(fa[il][0], fb[JB + 1][0], acc[il][JB + 1], 0, 0, 0); \
        acc[il][JB]     = __builtin_amdgcn_mfma_f32_16x16x32_bf16(fa[il][1], fb[JB][1], acc[il][JB], 0, 0, 0); \
        acc[il][JB + 1] = __builtin_amdgcn_mfma_f32_16x16x32_bf16(fa[il][1], fb[JB + 1][1], acc[il][JB + 1], 0, 0, 0); \
    } } while (0)

#define TILE2(kt, b, nb) do { \
    /* p0: read A all + B all; stage kt+1's {A2,A3,B1} -> nb */ \
    _Pragma("unroll") \
    for (int il = 0; il < 4; ++il) { LDA2(fa[il][0], b, il, k0off); LDA2(fa[il][1], b, il, k1off); } \
    _Pragma("unroll") \
    for (int jl = 0; jl < 4; ++jl) { LDB2(fb[jl][0], b, jl, k0off); LDB2(fb[jl][1], b, jl, k1off); } \
    if ((kt) < 15) { STA2(nb, (kt) + 1, 2); STA2(nb, (kt) + 1, 3); STB2(nb, (kt) + 1, 1); } \
    asm volatile("s_waitcnt lgkmcnt(0)" ::: "memory"); \
    __builtin_amdgcn_sched_barrier(0); \
    __builtin_amdgcn_s_setprio(1); MM2(0); __builtin_amdgcn_s_setprio(0); \
    __builtin_amdgcn_s_barrier(); \
    /* p1: no reads; stage kt+2's {A0,A1,B0} -> b */ \
    if ((kt) < 14) { STA2(b, (kt) + 2, 0); STA2(b, (kt) + 2, 1); STB2(b, (kt) + 2, 0); } \
    __builtin_amdgcn_s_setprio(1); MM2(2); __builtin_amdgcn_s_setprio(0); \
    if ((kt) < 14) { asm volatile("s_waitcnt vmcnt(3)" ::: "memory"); } \
    else           { asm volatile("s_waitcnt vmcnt(0)" ::: "memory"); } \
    __builtin_amdgcn_s_barrier(); \
} while (0)

#pragma unroll 1
    for (int kt2 = 0; kt2 < 16; kt2 += 2) {
        TILE2(kt2, 0, 1);
        TILE2(kt2 + 1, 1, 0);
    }
#undef TILE2
#undef MM2
#undef STA2
#undef STB2
#undef LDA2
#undef LDB2

    const int colL = lane & 15;
    const int rowQ = (lane >> 4) * 4;
#pragma unroll
    for (int jl = 0; jl < 4; ++jl) {
        const int n = n0 + wn * 64 + jl * 16 + colL;
        const float bv = bout[n];
#pragma unroll
        for (int il = 0; il < 4; ++il) {
            const int mbase = m0 + wm * 64 + il * 16 + rowQ;
#pragma unroll
            for (int r = 0; r < 4; ++r)
                Out[(size_t)(mbase + r) * DM + n] = acc[il][jl][r] + bv;
        }
    }
}

extern "C" void kernel_launch(void* const* d_in, const int* in_sizes, int n_in,
                              void* d_out, int out_size, void* d_ws, size_t ws_size,
                              hipStream_t stream) {
    const float* x     = (const float*)d_in[0];   // [4,4096,1024] fp32
    const float* Wproj = (const float*)d_in[1];   // [1024,3072]   fp32
    const float* bproj = (const float*)d_in[2];   // [3072]        fp32
    const float* Wout  = (const float*)d_in[3];   // [1024,1024]   fp32
    const float* bout  = (const float*)d_in[4];   // [1024]        fp32
    float* out = (float*)d_out;                   // [4,4096,1024] fp32 (64 MB)

    unsigned short* Xb  = (unsigned short*)d_out; // shorts [0,16M): Xbf16 (phases 1-3)
    unsigned short* WgT   = (unsigned short*)d_ws;
    unsigned short* WoT   = WgT + MEG;
    unsigned short* WoutT = WgT + 2 * MEG;
    unsigned short* Hws   = WgT + 3 * MEG;

    const bool big_ws = ws_size >= (size_t)19 * MEG * 2;

    unsigned short* Hlo = big_ws ? Hws : ((unsigned short*)d_out + 16 * MEG);
    unsigned short* Hhi = big_ws ? (Hws + (size_t)8192 * DM) : Hws;

    // 1) Xbf16 (d_out lo) <- fp32 x
    conv_x<<<(MTOT * DM) / (256 * 8), 256, 0, stream>>>(x, Xb);

    // 2) transposed bf16 weight panels -> ws
    transpose_w<<<dim3(32, 32, 3), dim3(32, 8, 1), 0, stream>>>(Wproj, Wout, WgT);

    // 3) H = (X@Wg + bg) * sigmoid(X@Wo + bo), stored split across Hlo/Hhi
    gemm1_fused<<<512, 512, 0, stream>>>(Xb, WgT, WoT, bproj, Hlo, Hhi);

    // 4) out = H @ Wout + b_out
    if (big_ws) {
        gemm2<<<512, 512, 0, stream>>>(Hlo, Hhi, WoutT, bout, out, 0);
    } else {
        // lo half first (reads d_out-hi H, writes d_out-lo out: disjoint),
        // then hi half (reads only ws, overwrites the now-dead H-lo region)
        gemm2<<<256, 512, 0, stream>>>(Hlo, Hhi, WoutT, bout, out, 0);
        gemm2<<<256, 512, 0, stream>>>(Hlo, Hhi, WoutT, bout, out, 8192);
    }
}